// Round 1
// baseline (125.606 us; speedup 1.0000x reference)
//
#include <hip/hip_runtime.h>
#include <hip/hip_bf16.h>
#include <cstddef>

#define HW 2304
#define CD 256

typedef __bf16 bf16;
typedef bf16 bf16x8 __attribute__((ext_vector_type(8)));
typedef float f32x4 __attribute__((ext_vector_type(4)));

__device__ __forceinline__ unsigned short f2bf(float f) {
    unsigned u = __float_as_uint(f);
    u += 0x7fffu + ((u >> 16) & 1u);
    return (unsigned short)(u >> 16);
}
__device__ __forceinline__ unsigned fkey(float f) {
    unsigned u = __float_as_uint(f);
    return (u & 0x80000000u) ? ~u : (u | 0x80000000u);
}
__device__ __forceinline__ float fdec(unsigned k) {
    unsigned u = (k & 0x80000000u) ? (k ^ 0x80000000u) : ~k;
    return __uint_as_float(u);
}

// ---- pass 1a: convert the 4 fine memories to bf16, layout [b][t][n][c] ----
__global__ void convert_mems(const float* __restrict__ g0, const float* __restrict__ g1,
                             const float* __restrict__ l0, const float* __restrict__ l1,
                             unsigned short* __restrict__ outB) {
    const int t = blockIdx.y;
    const float* src = t == 0 ? g0 : t == 1 ? g1 : t == 2 ? l0 : l1;
    const size_t i4 = (size_t)blockIdx.x * 256 + threadIdx.x;   // float4 index
    const size_t per_b = (size_t)HW * CD;                       // 589824
    const size_t e = i4 * 4;
    const int b = (int)(e / per_b);
    const size_t rem = e - (size_t)b * per_b;
    float4 v = ((const float4*)src)[i4];
    ushort4 o;
    o.x = f2bf(v.x); o.y = f2bf(v.y); o.z = f2bf(v.z); o.w = f2bf(v.w);
    *(ushort4*)(outB + (size_t)(b * 4 + t) * per_b + rem) = o;
}

// ---- pass 1b: transpose k (B,C,HW) f32 -> kT (B,HW,C) bf16 ----
__global__ void transpose_k(const float* __restrict__ k, unsigned short* __restrict__ kT) {
    __shared__ float tile[32][33];
    const int bz = blockIdx.z;
    const int m0 = blockIdx.x * 32;
    const int c0 = blockIdx.y * 32;
    const int tx = threadIdx.x, ty = threadIdx.y;   // block (32,8)
    const float* kb = k + (size_t)bz * CD * HW;
    #pragma unroll
    for (int s = 0; s < 32; s += 8)
        tile[ty + s][tx] = kb[(size_t)(c0 + ty + s) * HW + m0 + tx];
    __syncthreads();
    unsigned short* kTb = kT + (size_t)bz * HW * CD;
    #pragma unroll
    for (int s = 0; s < 32; s += 8)
        kTb[(size_t)(m0 + ty + s) * CD + c0 + tx] = f2bf(tile[tx][ty + s]);
}

// ---- pass 2: tiled bf16 MFMA GEMM + (optional sds scale) + column max ----
// grid (18, 18, 16): x = m-tile, y = n-tile, z = b*4+t
__global__ __launch_bounds__(256, 2)
void fine_gemm(const unsigned short* __restrict__ memsB,
               const unsigned short* __restrict__ kT,
               const float* __restrict__ sds,
               unsigned* __restrict__ scratch) {
    __shared__ unsigned short Al[128][32];   // [n][k] 8KB
    __shared__ unsigned short Bl[128][32];   // [m][k] 8KB
    const int z = blockIdx.z;
    const int b = z >> 2, t = z & 3;
    const int n0 = blockIdx.y * 128;
    const int m0 = blockIdx.x * 128;
    const int tid = threadIdx.x;
    const int lane = tid & 63;
    const int w = tid >> 6;
    const int wrow = w >> 1, wcol = w & 1;

    const unsigned short* Ag = memsB + (size_t)z * (HW * CD);
    const unsigned short* Bg = kT + (size_t)b * (HW * CD);

    const int srow = lane >> 2;          // 0..15: row within 16-row stripe
    const int scol = (lane & 3) * 8;     // element offset within row

    f32x4 acc[4][4] = {};

    for (int kt = 0; kt < CD / 32; ++kt) {
        #pragma unroll
        for (int s = 0; s < 2; ++s) {
            const int r = w * 32 + s * 16;   // wave-uniform 16-row stripe base
            const unsigned short* ga = Ag + (size_t)(n0 + r + srow) * CD + kt * 32 + scol;
            __builtin_amdgcn_global_load_lds(
                (const __attribute__((address_space(1))) unsigned int*)ga,
                (__attribute__((address_space(3))) unsigned int*)&Al[r][0], 16, 0, 0);
            const unsigned short* gb = Bg + (size_t)(m0 + r + srow) * CD + kt * 32 + scol;
            __builtin_amdgcn_global_load_lds(
                (const __attribute__((address_space(1))) unsigned int*)gb,
                (__attribute__((address_space(3))) unsigned int*)&Bl[r][0], 16, 0, 0);
        }
        __syncthreads();
        const int lr = lane & 15;
        const int lk = (lane >> 4) * 8;
        bf16x8 af[4], bfr[4];
        #pragma unroll
        for (int i = 0; i < 4; ++i)
            af[i] = *(const bf16x8*)&Al[wrow * 64 + i * 16 + lr][lk];
        #pragma unroll
        for (int j = 0; j < 4; ++j)
            bfr[j] = *(const bf16x8*)&Bl[wcol * 64 + j * 16 + lr][lk];
        #pragma unroll
        for (int i = 0; i < 4; ++i)
            #pragma unroll
            for (int j = 0; j < 4; ++j)
                acc[i][j] = __builtin_amdgcn_mfma_f32_16x16x32_bf16(af[i], bfr[j], acc[i][j], 0, 0, 0);
        __syncthreads();
    }

    // epilogue: sds scale for local memories (t = 2, 3)
    if (t >= 2) {
        const float* sb = sds + (size_t)b * HW * HW;
        #pragma unroll
        for (int i = 0; i < 4; ++i) {
            #pragma unroll
            for (int j = 0; j < 4; ++j) {
                #pragma unroll
                for (int r = 0; r < 4; ++r) {
                    const int n = n0 + wrow * 64 + i * 16 + (lane >> 4) * 4 + r;
                    const int m = m0 + wcol * 64 + j * 16 + (lane & 15);
                    acc[i][j][r] *= sb[(size_t)n * HW + m];
                }
            }
        }
    }

    // column max over the n (row) dimension, then device atomicMax
    #pragma unroll
    for (int j = 0; j < 4; ++j) {
        float v = acc[0][j][0];
        #pragma unroll
        for (int i = 0; i < 4; ++i)
            #pragma unroll
            for (int r = 0; r < 4; ++r)
                v = fmaxf(v, acc[i][j][r]);
        v = fmaxf(v, __shfl_xor(v, 16));
        v = fmaxf(v, __shfl_xor(v, 32));
        if (lane < 16) {
            const int m = m0 + wcol * 64 + j * 16 + lane;
            atomicMax(&scratch[(size_t)z * HW + m], fkey(v));
        }
    }
}

// ---- pass 3: decode fine maxes + exact f32 coarse dots ----
__global__ void finalize(const unsigned* __restrict__ scratch,
                         const float* __restrict__ kf,
                         const float* __restrict__ c0, const float* __restrict__ c1,
                         const float* __restrict__ c2, const float* __restrict__ c3,
                         const float* __restrict__ c4, const float* __restrict__ c5,
                         float* __restrict__ out) {
    const int b = blockIdx.y;
    const int m = blockIdx.x * 256 + threadIdx.x;
    #pragma unroll
    for (int t = 0; t < 4; ++t)
        out[((size_t)b * 10 + t) * HW + m] = fdec(scratch[(size_t)(b * 4 + t) * HW + m]);
    float a0 = 0, a1 = 0, a2 = 0, a3 = 0, a4 = 0, a5 = 0;
    const float* kb = kf + (size_t)b * CD * HW;
    for (int c = 0; c < CD; ++c) {
        const float kv = kb[(size_t)c * HW + m];
        a0 = fmaf(c0[b * CD + c], kv, a0);
        a1 = fmaf(c1[b * CD + c], kv, a1);
        a2 = fmaf(c2[b * CD + c], kv, a2);
        a3 = fmaf(c3[b * CD + c], kv, a3);
        a4 = fmaf(c4[b * CD + c], kv, a4);
        a5 = fmaf(c5[b * CD + c], kv, a5);
    }
    out[((size_t)b * 10 + 4) * HW + m] = a0;
    out[((size_t)b * 10 + 5) * HW + m] = a1;
    out[((size_t)b * 10 + 6) * HW + m] = a2;
    out[((size_t)b * 10 + 7) * HW + m] = a3;
    out[((size_t)b * 10 + 8) * HW + m] = a4;
    out[((size_t)b * 10 + 9) * HW + m] = a5;
}

extern "C" void kernel_launch(void* const* d_in, const int* in_sizes, int n_in,
                              void* d_out, int out_size, void* d_ws, size_t ws_size,
                              hipStream_t stream) {
    const float* norm_key = (const float*)d_in[0];
    const float* gbg = (const float*)d_in[1];
    const float* gfg = (const float*)d_in[2];
    const float* lbg = (const float*)d_in[3];
    const float* lfg = (const float*)d_in[4];
    const float* obg = (const float*)d_in[5];
    const float* ofg = (const float*)d_in[6];
    const float* sbg = (const float*)d_in[7];
    const float* sfg = (const float*)d_in[8];
    const float* lgbg = (const float*)d_in[9];
    const float* lgfg = (const float*)d_in[10];
    const float* sds = (const float*)d_in[11];
    float* out = (float*)d_out;

    // ws layout: [scratch keys 16*2304 u32][memsB bf16 16*2304*256][kT bf16 4*2304*256]
    unsigned* scratch = (unsigned*)d_ws;
    const size_t scratch_bytes = (size_t)16 * HW * sizeof(unsigned);                 // 147456
    unsigned short* memsB = (unsigned short*)((char*)d_ws + scratch_bytes);
    const size_t mems_bytes = (size_t)16 * HW * CD * sizeof(unsigned short);         // ~18.9 MB
    unsigned short* kT = (unsigned short*)((char*)d_ws + scratch_bytes + mems_bytes); // ~4.7 MB

    hipMemsetAsync(d_ws, 0, scratch_bytes, stream);
    convert_mems<<<dim3(2304, 4), 256, 0, stream>>>(gbg, gfg, lbg, lfg, memsB);
    transpose_k<<<dim3(72, 8, 4), dim3(32, 8), 0, stream>>>(norm_key, kT);
    fine_gemm<<<dim3(18, 18, 16), 256, 0, stream>>>(memsB, kT, sds, scratch);
    finalize<<<dim3(9, 4), 256, 0, stream>>>(scratch, norm_key, obg, ofg, sbg, sfg, lgbg, lgfg, out);
}

// Round 2
// 116.438 us; speedup vs baseline: 1.0787x; 1.0787x over previous
//
#include <hip/hip_runtime.h>
#include <hip/hip_bf16.h>
#include <cstddef>

#define HW 2304
#define CD 256

typedef __bf16 bf16;
typedef bf16 bf16x8 __attribute__((ext_vector_type(8)));
typedef float f32x4 __attribute__((ext_vector_type(4)));

__device__ __forceinline__ unsigned short f2bf(float f) {
    unsigned u = __float_as_uint(f);
    u += 0x7fffu + ((u >> 16) & 1u);
    return (unsigned short)(u >> 16);
}
__device__ __forceinline__ unsigned fkey(float f) {
    unsigned u = __float_as_uint(f);
    return (u & 0x80000000u) ? ~u : (u | 0x80000000u);
}
__device__ __forceinline__ float fdec(unsigned k) {
    unsigned u = (k & 0x80000000u) ? (k ^ 0x80000000u) : ~k;
    return __uint_as_float(u);
}

// ---- pass 1a: convert the 4 fine memories to bf16, layout [b][t][n][c] ----
__global__ void convert_mems(const float* __restrict__ g0, const float* __restrict__ g1,
                             const float* __restrict__ l0, const float* __restrict__ l1,
                             unsigned short* __restrict__ outB) {
    const int t = blockIdx.y;
    const float* src = t == 0 ? g0 : t == 1 ? g1 : t == 2 ? l0 : l1;
    const size_t i4 = (size_t)blockIdx.x * 256 + threadIdx.x;   // float4 index
    const size_t per_b = (size_t)HW * CD;                       // 589824
    const size_t e = i4 * 4;
    const int b = (int)(e / per_b);
    const size_t rem = e - (size_t)b * per_b;
    float4 v = ((const float4*)src)[i4];
    ushort4 o;
    o.x = f2bf(v.x); o.y = f2bf(v.y); o.z = f2bf(v.z); o.w = f2bf(v.w);
    *(ushort4*)(outB + (size_t)(b * 4 + t) * per_b + rem) = o;
}

// ---- pass 1b: transpose k (B,C,HW) f32 -> kT (B,HW,C) bf16 ----
__global__ void transpose_k(const float* __restrict__ k, unsigned short* __restrict__ kT) {
    __shared__ float tile[32][33];
    const int bz = blockIdx.z;
    const int m0 = blockIdx.x * 32;
    const int c0 = blockIdx.y * 32;
    const int tx = threadIdx.x, ty = threadIdx.y;   // block (32,8)
    const float* kb = k + (size_t)bz * CD * HW;
    #pragma unroll
    for (int s = 0; s < 32; s += 8)
        tile[ty + s][tx] = kb[(size_t)(c0 + ty + s) * HW + m0 + tx];
    __syncthreads();
    unsigned short* kTb = kT + (size_t)bz * HW * CD;
    #pragma unroll
    for (int s = 0; s < 32; s += 8)
        kTb[(size_t)(m0 + ty + s) * CD + c0 + tx] = f2bf(tile[tx][ty + s]);
}

// ---- pass 2: dual-t tiled bf16 MFMA GEMM + (optional sds scale) + column max ----
// grid (18, 18, 8): x = m-tile, y = n-tile, z = b*2 + p  (p=0 -> t{0,1}, p=1 -> t{2,3})
// 2-phase double-buffered schedule: stage(kt+1) issued before compute(kt),
// single __syncthreads() per K-step (implicit vmcnt(0) drain covers prefetch).
__global__ __launch_bounds__(256, 2)
void fine_gemm(const unsigned short* __restrict__ memsB,
               const unsigned short* __restrict__ kT,
               const float* __restrict__ sds,
               unsigned* __restrict__ scratch) {
    __shared__ unsigned short A0l[2][128][32];   // 16KB
    __shared__ unsigned short A1l[2][128][32];   // 16KB
    __shared__ unsigned short Bl[2][128][32];    // 16KB
    const int z = blockIdx.z;
    const int b = z >> 1, p = z & 1;
    const int t0 = p * 2;
    const int n0 = blockIdx.y * 128;
    const int m0 = blockIdx.x * 128;
    const int tid = threadIdx.x;
    const int lane = tid & 63;
    const int w = tid >> 6;
    const int wrow = w >> 1, wcol = w & 1;

    const unsigned short* A0g = memsB + (size_t)(b * 4 + t0) * (HW * CD);
    const unsigned short* A1g = memsB + (size_t)(b * 4 + t0 + 1) * (HW * CD);
    const unsigned short* Bg = kT + (size_t)b * (HW * CD);

    const int srow = lane >> 2;          // 0..15
    const int scol = (lane & 3) * 8;     // element offset (16B chunks)

    f32x4 acc0[4][4] = {};
    f32x4 acc1[4][4] = {};

#define STAGE(buf, kt)                                                                     \
    do {                                                                                   \
        _Pragma("unroll")                                                                  \
        for (int s = 0; s < 2; ++s) {                                                      \
            const int r = w * 32 + s * 16;                                                 \
            const unsigned short* ga = A0g + (size_t)(n0 + r + srow) * CD + (kt) * 32 + scol; \
            __builtin_amdgcn_global_load_lds(                                              \
                (const __attribute__((address_space(1))) unsigned int*)ga,                 \
                (__attribute__((address_space(3))) unsigned int*)&A0l[buf][r][0], 16, 0, 0); \
            const unsigned short* gb = A1g + (size_t)(n0 + r + srow) * CD + (kt) * 32 + scol; \
            __builtin_amdgcn_global_load_lds(                                              \
                (const __attribute__((address_space(1))) unsigned int*)gb,                 \
                (__attribute__((address_space(3))) unsigned int*)&A1l[buf][r][0], 16, 0, 0); \
            const unsigned short* gc = Bg + (size_t)(m0 + r + srow) * CD + (kt) * 32 + scol; \
            __builtin_amdgcn_global_load_lds(                                              \
                (const __attribute__((address_space(1))) unsigned int*)gc,                 \
                (__attribute__((address_space(3))) unsigned int*)&Bl[buf][r][0], 16, 0, 0); \
        }                                                                                  \
    } while (0)

    STAGE(0, 0);
    __syncthreads();

    const int lr = lane & 15;
    const int lk = (lane >> 4) * 8;

    #pragma unroll
    for (int kt = 0; kt < 8; ++kt) {
        const int cur = kt & 1;
        if (kt < 7) STAGE(cur ^ 1, kt + 1);
        bf16x8 a0f[4], a1f[4], bfr[4];
        #pragma unroll
        for (int i = 0; i < 4; ++i) {
            a0f[i] = *(const bf16x8*)&A0l[cur][wrow * 64 + i * 16 + lr][lk];
            a1f[i] = *(const bf16x8*)&A1l[cur][wrow * 64 + i * 16 + lr][lk];
        }
        #pragma unroll
        for (int j = 0; j < 4; ++j)
            bfr[j] = *(const bf16x8*)&Bl[cur][wcol * 64 + j * 16 + lr][lk];
        #pragma unroll
        for (int i = 0; i < 4; ++i) {
            #pragma unroll
            for (int j = 0; j < 4; ++j) {
                acc0[i][j] = __builtin_amdgcn_mfma_f32_16x16x32_bf16(a0f[i], bfr[j], acc0[i][j], 0, 0, 0);
                acc1[i][j] = __builtin_amdgcn_mfma_f32_16x16x32_bf16(a1f[i], bfr[j], acc1[i][j], 0, 0, 0);
            }
        }
        if (kt < 7) __syncthreads();
    }
#undef STAGE

    // epilogue: sds scale for the local pair (p == 1), one read serves both t's
    if (p == 1) {
        const float* sb = sds + (size_t)b * HW * HW;
        #pragma unroll
        for (int i = 0; i < 4; ++i) {
            #pragma unroll
            for (int j = 0; j < 4; ++j) {
                #pragma unroll
                for (int r = 0; r < 4; ++r) {
                    const int n = n0 + wrow * 64 + i * 16 + (lane >> 4) * 4 + r;
                    const int m = m0 + wcol * 64 + j * 16 + (lane & 15);
                    const float sv = sb[(size_t)n * HW + m];
                    acc0[i][j][r] *= sv;
                    acc1[i][j][r] *= sv;
                }
            }
        }
    }

    // column max over the n (row) dimension per t, then device atomicMax
    #pragma unroll
    for (int j = 0; j < 4; ++j) {
        float v0 = acc0[0][j][0];
        float v1 = acc1[0][j][0];
        #pragma unroll
        for (int i = 0; i < 4; ++i) {
            #pragma unroll
            for (int r = 0; r < 4; ++r) {
                v0 = fmaxf(v0, acc0[i][j][r]);
                v1 = fmaxf(v1, acc1[i][j][r]);
            }
        }
        v0 = fmaxf(v0, __shfl_xor(v0, 16));
        v0 = fmaxf(v0, __shfl_xor(v0, 32));
        v1 = fmaxf(v1, __shfl_xor(v1, 16));
        v1 = fmaxf(v1, __shfl_xor(v1, 32));
        if (lane < 16) {
            const int m = m0 + wcol * 64 + j * 16 + lane;
            atomicMax(&scratch[(size_t)(b * 4 + t0) * HW + m], fkey(v0));
            atomicMax(&scratch[(size_t)(b * 4 + t0 + 1) * HW + m], fkey(v1));
        }
    }
}

// ---- pass 3: decode fine maxes + exact f32 coarse dots ----
__global__ void finalize(const unsigned* __restrict__ scratch,
                         const float* __restrict__ kf,
                         const float* __restrict__ c0, const float* __restrict__ c1,
                         const float* __restrict__ c2, const float* __restrict__ c3,
                         const float* __restrict__ c4, const float* __restrict__ c5,
                         float* __restrict__ out) {
    const int b = blockIdx.y;
    const int m = blockIdx.x * 256 + threadIdx.x;
    #pragma unroll
    for (int t = 0; t < 4; ++t)
        out[((size_t)b * 10 + t) * HW + m] = fdec(scratch[(size_t)(b * 4 + t) * HW + m]);
    float a0 = 0, a1 = 0, a2 = 0, a3 = 0, a4 = 0, a5 = 0;
    const float* kb = kf + (size_t)b * CD * HW;
    for (int c = 0; c < CD; ++c) {
        const float kv = kb[(size_t)c * HW + m];
        a0 = fmaf(c0[b * CD + c], kv, a0);
        a1 = fmaf(c1[b * CD + c], kv, a1);
        a2 = fmaf(c2[b * CD + c], kv, a2);
        a3 = fmaf(c3[b * CD + c], kv, a3);
        a4 = fmaf(c4[b * CD + c], kv, a4);
        a5 = fmaf(c5[b * CD + c], kv, a5);
    }
    out[((size_t)b * 10 + 4) * HW + m] = a0;
    out[((size_t)b * 10 + 5) * HW + m] = a1;
    out[((size_t)b * 10 + 6) * HW + m] = a2;
    out[((size_t)b * 10 + 7) * HW + m] = a3;
    out[((size_t)b * 10 + 8) * HW + m] = a4;
    out[((size_t)b * 10 + 9) * HW + m] = a5;
}

extern "C" void kernel_launch(void* const* d_in, const int* in_sizes, int n_in,
                              void* d_out, int out_size, void* d_ws, size_t ws_size,
                              hipStream_t stream) {
    const float* norm_key = (const float*)d_in[0];
    const float* gbg = (const float*)d_in[1];
    const float* gfg = (const float*)d_in[2];
    const float* lbg = (const float*)d_in[3];
    const float* lfg = (const float*)d_in[4];
    const float* obg = (const float*)d_in[5];
    const float* ofg = (const float*)d_in[6];
    const float* sbg = (const float*)d_in[7];
    const float* sfg = (const float*)d_in[8];
    const float* lgbg = (const float*)d_in[9];
    const float* lgfg = (const float*)d_in[10];
    const float* sds = (const float*)d_in[11];
    float* out = (float*)d_out;

    // ws layout: [scratch keys 16*2304 u32][memsB bf16 16*2304*256][kT bf16 4*2304*256]
    unsigned* scratch = (unsigned*)d_ws;
    const size_t scratch_bytes = (size_t)16 * HW * sizeof(unsigned);
    unsigned short* memsB = (unsigned short*)((char*)d_ws + scratch_bytes);
    const size_t mems_bytes = (size_t)16 * HW * CD * sizeof(unsigned short);
    unsigned short* kT = (unsigned short*)((char*)d_ws + scratch_bytes + mems_bytes);

    hipMemsetAsync(d_ws, 0, scratch_bytes, stream);
    convert_mems<<<dim3(2304, 4), 256, 0, stream>>>(gbg, gfg, lbg, lfg, memsB);
    transpose_k<<<dim3(72, 8, 4), dim3(32, 8), 0, stream>>>(norm_key, kT);
    fine_gemm<<<dim3(18, 18, 8), 256, 0, stream>>>(memsB, kT, sds, scratch);
    finalize<<<dim3(9, 4), 256, 0, stream>>>(scratch, norm_key, obg, ofg, sbg, sfg, lgbg, lgfg, out);
}